// Round 5
// baseline (143.270 us; speedup 1.0000x reference)
//
#include <hip/hip_runtime.h>

// HMM forward: alpha_t = (alpha_{t-1} @ A) * B[:, obs[t]]; out[t][s] = alpha_t[s].
// S=2048, T=8192, 512 symbols, fp32.
//
// alpha decays ~512x/step -> exact-zero underflow at t~17; after the first
// all-zero row every later row is zero (verified R1-R12, absmax 1e-38).
// Honest recurrence + all-zero detection + zero tail.
//
// R12 post-mortem (68.5us): serialize-behind-go worked (occupancy trace shows
// fillers resident then exiting) but the 192-block fill ran at only ~1.9TB/s
// (~10 GB/s/CU) -- WORSE per-CU than R8's 64-block fill with PLAIN stores
// (~47 GB/s/CU). The changed variable is the store type: nontemporal (`nt`,
// no-allocate, bypasses L2 write-combining) vs plain write-allocate through
// the 8 XCD L2s. Theory: nt throttles per-CU write throughput ~3-4x.
// R13: revert filler+residue stores to PLAIN stores (R8-proven path); keep
// the R12 structure (192 fillers sleep-poll go-flag, fill rows [128,8192)
// after recurrence-done; compute blocks zero residue [lastRow+1,128)).
// Faster wake: s_sleep(8). Deadlock-free for arbitrary inputs: a compute
// block reaching t==FILL_START sets the go-flag BEFORE acquire-waiting on
// the fillers' done-counter.
//
// Recurrence (unchanged from R8): A slice lives in REGISTERS -- each lane's 16
// float4 of A are step-invariant; 64 VGPR/lane x 1024 threads = the block's
// whole 256KB slice. Consumers stream producer chunks directly (wave w owns
// chunks w,w+16,w+32,w+48; each lane batch-polls its 16 encoded alpha scalars,
// 8 lanes/address coalesced broadcast), FMA vs register A, shfl-reduce, ONE
// barrier, wave0 combines and publishes. s_nz is depth-4 parity.
// Encoding: enc = bits(a)+2^30 in [0x40000000,0x7F800000] (alpha in [0,1]);
// poison 0xAA.., zeros, and stale DECODED values all read not-ready.
// Post-loop: flag rendezvous, in-place decode, residue zero-fill.
//
// flag[] layout (d_ws): [0..63] per-block rendezvous; [64] filler done-count
// (release/acquire); [65] go-flag for fillers (relaxed).

#define S     2048
#define T     8192
#define NSYM  512
#define NCBLK 64                         // compute blocks
#define NFILL 192                        // filler blocks
#define NBLK  (NCBLK + NFILL)
#define NTHR  1024
#define READY 0x40000000
#define FILL_START 128                   // rows >= this are filler-owned
#define ROWS_PER_FILL ((T - FILL_START) / NFILL)   // 8064/192 = 42 exactly

typedef int   v4i __attribute__((ext_vector_type(4)));
typedef float v4f __attribute__((ext_vector_type(4)));

__device__ __forceinline__ v4i load_coherent_i4(const int* p) {
    v4i r;
    asm volatile("global_load_dwordx4 %0, %1, off sc0 sc1\n\ts_waitcnt vmcnt(0)"
                 : "=v"(r) : "v"(p) : "memory");
    return r;
}
__device__ __forceinline__ void store_coherent_i4(int* p, v4i v) {
    asm volatile("global_store_dwordx4 %0, %1, off sc0 sc1"
                 :: "v"(p), "v"(v) : "memory");
}

// 4 coherent scalar loads from one base (+0,+32,+64,+96 bytes), NO waitcnt.
#define POLL4(e0,e1,e2,e3,bp)                                              \
    asm volatile("global_load_dword %0, %4, off sc0 sc1\n\t"               \
                 "global_load_dword %1, %4, off offset:32 sc0 sc1\n\t"     \
                 "global_load_dword %2, %4, off offset:64 sc0 sc1\n\t"     \
                 "global_load_dword %3, %4, off offset:96 sc0 sc1"         \
                 : "=&v"(e0), "=&v"(e1), "=&v"(e2), "=&v"(e3)              \
                 : "v"(bp) : "memory")

__global__ void __launch_bounds__(NTHR) hmm_fwd(
    const int*   __restrict__ obs,
    const float* __restrict__ A,
    const float* __restrict__ B,
    const float* __restrict__ pi,
    float*       __restrict__ out,
    unsigned*    __restrict__ flag)
{
    __shared__ float4 s_wpart[16][8];    // 2 KB per-wave partials
    __shared__ int    s_nz[4];           // depth-4 parity "row nonzero"

    const int tx   = threadIdx.x;
    const int b    = blockIdx.x;

    // ----- filler blocks: WAIT for recurrence-done, then zero rows [128,8192) -----
    if (b >= NCBLK) {
        if (tx == 0) {
            while (__hip_atomic_load(&flag[NCBLK + 1], __ATOMIC_RELAXED,
                                     __HIP_MEMORY_SCOPE_AGENT) == 0u)
                __builtin_amdgcn_s_sleep(8);       // ~0.2us cadence, 1 lane
        }
        __syncthreads();
        const int fb = b - NCBLK;
        v4f* dst = (v4f*)(out + (size_t)(FILL_START + fb * ROWS_PER_FILL) * S);
        const int n4 = ROWS_PER_FILL * (S / 4);       // 21504 = 21 * 1024
        const v4f z = {0.f, 0.f, 0.f, 0.f};
        for (int i = tx; i < n4; i += NTHR)
            dst[i] = z;                               // PLAIN stores (R8-proven fast path)
        __syncthreads();                              // all lanes' stores issued
        if (tx == 0) {
            __threadfence();                          // stores visible device-wide
            __hip_atomic_fetch_add(&flag[NCBLK], 1u,
                                   __ATOMIC_RELEASE, __HIP_MEMORY_SCOPE_AGENT);
        }
        return;
    }

    // ---------------- compute blocks (recurrence identical to R8) -------------
    const int lane = tx & 63;
    const int w    = tx >> 6;            // wave id 0..15
    const int jl4  = lane & 7;           // col float4 within block (0..7)
    const int r_l  = lane >> 3;          // row-within-group (0..7)
    const int col4 = b * 8 + jl4;
    const float4* A4 = (const float4*)A;

    // hoist the block's A slice into registers: a[q][s] = A4[i][col4],
    // i = (w+16q)*32 + s*8 + r_l  (step-invariant!)
    float4 a_reg[4][4];
    #pragma unroll
    for (int q = 0; q < 4; ++q)
        #pragma unroll
        for (int s = 0; s < 4; ++s) {
            const int i = (w + 16 * q) * 32 + s * 8 + r_l;
            a_reg[q][s] = A4[(size_t)i * (S / 4) + col4];
        }

    // step 0: publish encoded alpha0 chunk = pi * B[:, obs[0]]
    if (tx < 8) {
        const int o0 = obs[0];
        const int j  = b * 32 + tx * 4;
        v4i e;
        e.x = __float_as_int(pi[j + 0] * B[(size_t)(j + 0) * NSYM + o0]) + READY;
        e.y = __float_as_int(pi[j + 1] * B[(size_t)(j + 1) * NSYM + o0]) + READY;
        e.z = __float_as_int(pi[j + 2] * B[(size_t)(j + 2) * NSYM + o0]) + READY;
        e.w = __float_as_int(pi[j + 3] * B[(size_t)(j + 3) * NSYM + o0]) + READY;
        store_coherent_i4((int*)out + j, e);
    }
    if (tx == 0) { s_nz[0] = 0; s_nz[1] = 0; s_nz[2] = 0; s_nz[3] = 0; }
    __syncthreads();

    int lastRow = T - 1;

    for (int t = 1; t < T; ++t) {
        // safety gate (never taken for benchmark input): before writing any
        // filler-owned row, release the fillers (go-flag FIRST -- deadlock-free)
        // then acquire-wait for their zeros to be globally visible.
        if (t == FILL_START) {
            if (tx == 0) {
                __hip_atomic_store(&flag[NCBLK + 1], 1u, __ATOMIC_RELAXED,
                                   __HIP_MEMORY_SCOPE_AGENT);
                while (__hip_atomic_load(&flag[NCBLK], __ATOMIC_ACQUIRE,
                                         __HIP_MEMORY_SCOPE_AGENT) < NFILL)
                    __builtin_amdgcn_s_sleep(8);
            }
            __syncthreads();
        }

        // ---- emission prefetch (wave0 lanes; same lanes publish later) ----
        float em0 = 0.f, em1 = 0.f, em2 = 0.f, em3 = 0.f;
        if (tx < 8) {
            const int o = obs[t];
            const int j = b * 32 + tx * 4;
            em0 = B[(size_t)(j + 0) * NSYM + o];
            em1 = B[(size_t)(j + 1) * NSYM + o];
            em2 = B[(size_t)(j + 2) * NSYM + o];
            em3 = B[(size_t)(j + 3) * NSYM + o];
        }

        // ---- batch-poll this wave's 16 encoded alpha scalars of row t-1 ----
        const int* rb = (const int*)(out + (size_t)(t - 1) * S) + r_l;
        const int* b0 = rb + (w +  0) * 32;
        const int* b1 = rb + (w + 16) * 32;
        const int* b2 = rb + (w + 32) * 32;
        const int* b3 = rb + (w + 48) * 32;
        int e00, e01, e02, e03, e10, e11, e12, e13;
        int e20, e21, e22, e23, e30, e31, e32, e33;
        for (;;) {
            POLL4(e00, e01, e02, e03, b0);
            POLL4(e10, e11, e12, e13, b1);
            POLL4(e20, e21, e22, e23, b2);
            POLL4(e30, e31, e32, e33, b3);
            asm volatile("s_waitcnt vmcnt(0)" ::: "memory");
            const int m0 = (e00 < READY) | (e01 < READY) | (e02 < READY) | (e03 < READY);
            const int m1 = (e10 < READY) | (e11 < READY) | (e12 < READY) | (e13 < READY);
            const int m2 = (e20 < READY) | (e21 < READY) | (e22 < READY) | (e23 < READY);
            const int m3 = (e30 < READY) | (e31 < READY) | (e32 < READY) | (e33 < READY);
            if (!(m0 | m1 | m2 | m3)) break;
        }

        // ---- decode + FMA vs register-resident A ----
        float4 acc = make_float4(0.f, 0.f, 0.f, 0.f);
        int nzacc = 0;
        #define STEP1(E, Q, Ss)                                                \
            { const int d = (E) - READY; nzacc |= d;                           \
              const float af = __int_as_float(d);                              \
              acc.x = fmaf(af, a_reg[Q][Ss].x, acc.x);                         \
              acc.y = fmaf(af, a_reg[Q][Ss].y, acc.y);                         \
              acc.z = fmaf(af, a_reg[Q][Ss].z, acc.z);                         \
              acc.w = fmaf(af, a_reg[Q][Ss].w, acc.w); }
        STEP1(e00,0,0) STEP1(e01,0,1) STEP1(e02,0,2) STEP1(e03,0,3)
        STEP1(e10,1,0) STEP1(e11,1,1) STEP1(e12,1,2) STEP1(e13,1,3)
        STEP1(e20,2,0) STEP1(e21,2,1) STEP1(e22,2,2) STEP1(e23,2,3)
        STEP1(e30,3,0) STEP1(e31,3,1) STEP1(e32,3,2) STEP1(e33,3,3)
        #undef STEP1

        // in-wave reduce over lane bits 3,4,5 (the 8 r_l groups)
        #pragma unroll
        for (int m = 8; m <= 32; m <<= 1) {
            acc.x += __shfl_xor(acc.x, m);
            acc.y += __shfl_xor(acc.y, m);
            acc.z += __shfl_xor(acc.z, m);
            acc.w += __shfl_xor(acc.w, m);
        }
        if (lane < 8) s_wpart[w][lane] = acc;
        const unsigned long long nzm = __ballot(nzacc != 0);
        if (nzm != 0ull && lane == 0) s_nz[t & 3] = 1;   // benign same-value race
        if (tx == 0) s_nz[(t + 2) & 3] = 0;              // prep 2 steps ahead
        __syncthreads();                                 // the ONLY per-step barrier

        if (s_nz[t & 3] == 0) { lastRow = t - 1; break; }   // uniform everywhere

        // ---- wave0: combine 16 wave-partials, emission-multiply, publish ----
        if (tx < 64) {
            const int h = tx >> 3, c = tx & 7;
            float4 p = s_wpart[h][c];
            const float4 q4 = s_wpart[h + 8][c];
            p.x += q4.x; p.y += q4.y; p.z += q4.z; p.w += q4.w;
            #pragma unroll
            for (int m = 8; m <= 32; m <<= 1) {
                p.x += __shfl_xor(p.x, m);
                p.y += __shfl_xor(p.y, m);
                p.z += __shfl_xor(p.z, m);
                p.w += __shfl_xor(p.w, m);
            }
            if (tx < 8) {
                v4i e;
                e.x = __float_as_int(p.x * em0) + READY;
                e.y = __float_as_int(p.y * em1) + READY;
                e.z = __float_as_int(p.z * em2) + READY;
                e.w = __float_as_int(p.w * em3) + READY;
                store_coherent_i4((int*)(out + (size_t)t * S) + b * 32 + tx * 4, e);
            }
        }
        // no bottom barrier: next step's polls gate progress (R7/R8-proven).
    }

    // ---- release the fillers: recurrence traffic is over ----
    if (tx == 0)
        __hip_atomic_store(&flag[NCBLK + 1], 1u, __ATOMIC_RELAXED,
                           __HIP_MEMORY_SCOPE_AGENT);

    // ---- one-time rendezvous: nobody decodes rows still being poll-read ----
    if (tx == 0)
        __hip_atomic_store(&flag[b], 1u, __ATOMIC_RELAXED, __HIP_MEMORY_SCOPE_AGENT);
    if (tx < 64) {
        for (;;) {
            const unsigned f = __hip_atomic_load(&flag[tx], __ATOMIC_RELAXED,
                                                 __HIP_MEMORY_SCOPE_AGENT);
            if (__all(f == 1u)) break;
            __builtin_amdgcn_s_sleep(1);
        }
    }
    __syncthreads();

    // ---- decode own chunks of rows 0..lastRow in place ----
    for (int idx = tx; idx < (lastRow + 1) * 8; idx += NTHR) {
        const int r = idx >> 3, c = idx & 7;
        int* p = (int*)(out + (size_t)r * S) + b * 32 + c * 4;
        v4i e = load_coherent_i4(p);
        e.x -= READY; e.y -= READY; e.z -= READY; e.w -= READY;
        store_coherent_i4(p, e);
    }

    // ---- residue zero-fill: rows lastRow+1 .. FILL_START-1 (fillers own the rest)
    {
        const int zbeg = lastRow + 1;
        const int zend = (FILL_START > zbeg) ? FILL_START : zbeg;
        const size_t beg4 = (size_t)zbeg * (S / 4);
        const size_t end4 = (size_t)zend * (S / 4);
        const v4f z = {0.f, 0.f, 0.f, 0.f};
        v4f* o4 = (v4f*)out;
        for (size_t i = beg4 + (size_t)b * NTHR + tx; i < end4;
             i += (size_t)NCBLK * NTHR)
            o4[i] = z;                                // PLAIN stores
    }
}

extern "C" void kernel_launch(void* const* d_in, const int* in_sizes, int n_in,
                              void* d_out, int out_size, void* d_ws, size_t ws_size,
                              hipStream_t stream) {
    const int*   obs = (const int*)d_in[0];
    const float* A   = (const float*)d_in[1];
    const float* B   = (const float*)d_in[2];
    const float* pi  = (const float*)d_in[3];
    float* out = (float*)d_out;
    unsigned* flag = (unsigned*)d_ws;

    // d_ws is poisoned before every launch; rendezvous flags + filler
    // done-counter + go-flag must start at 0.
    (void)hipMemsetAsync(d_ws, 0, (size_t)(NCBLK + 2) * sizeof(unsigned), stream);

    hmm_fwd<<<dim3(NBLK), dim3(NTHR), 0, stream>>>(obs, A, B, pi, out, flag);
}

// Round 6
// 133.066 us; speedup vs baseline: 1.0767x; 1.0767x over previous
//
#include <hip/hip_runtime.h>

// HMM forward: alpha_t = (alpha_{t-1} @ A) * B[:, obs[t]]; out[t][s] = alpha_t[s].
// S=2048, T=8192, 512 symbols, fp32.
//
// alpha decays ~512x/step -> exact-zero underflow at t~17; after the first
// all-zero row every later row is zero (verified R1-R13, absmax 1e-38).
// Honest recurrence + all-zero detection + zero tail.
//
// R13 post-mortem: plain vs nontemporal stores moved 68.5->65.6us only --
// nt-store theory falsified. The wide fill still runs at ~1.5-2TB/s, OR the
// recurrence actually dominates (~40+us). Five rounds of guessing the
// recurrence/fill split; time to MEASURE it.
// R14: split into two stream-ordered kernels.
//   k1 hmm_fwd  (64 blocks): pure recurrence. No fillers, no go-flag, no
//     rendezvous, no decode. Publishes step-0 BEFORE the A-hoist (chain
//     starts ~4-5us earlier). On exit writes zstart=lastRow+1 to flag[0].
//   k2 hmm_tail (256 blocks): grid-stride over the whole out buffer;
//     rows < zstart: in-place decode (enc - READY); rows >= zstart: zero.
// The kernel boundary is a HW global barrier with full memory visibility:
// replaces the flag-rendezvous (whose 64-block coherent poll spin was itself
// fabric traffic) and makes the decode/zero pass embarrassingly parallel.
// rocprof now reports the recurrence and fill phases as separate dispatches.
//
// Recurrence core (R8-proven): A slice in REGISTERS (64 VGPR/lane x 1024 thr
// = block's whole 256KB step-invariant slice). Wave w polls chunks
// w,w+16,w+32,w+48 of row t-1 (16 encoded scalars/lane, 8-lane broadcast),
// FMA vs register A, shfl-reduce, ONE barrier, wave0 combines+publishes.
// s_nz depth-4 parity; all 64 blocks read the FULL row each step, so every
// block computes the identical lastRow.
// Encoding: enc = bits(a)+2^30 in [0x40000000,0x7F800000] (alpha in [0,1]);
// poison 0xAA.., zeros, and stale DECODED values all read not-ready.
//
// flag[] (d_ws): [0] = zstart (lastRow+1), written by every compute block
// (same value, benign); memset to 0 pre-launch.

#define S     2048
#define T     8192
#define NSYM  512
#define NCBLK 64                         // recurrence blocks
#define NTHR  1024
#define FBLK  256                        // tail-kernel blocks
#define READY 0x40000000

typedef int   v4i __attribute__((ext_vector_type(4)));
typedef float v4f __attribute__((ext_vector_type(4)));

__device__ __forceinline__ void store_coherent_i4(int* p, v4i v) {
    asm volatile("global_store_dwordx4 %0, %1, off sc0 sc1"
                 :: "v"(p), "v"(v) : "memory");
}

// 4 coherent scalar loads from one base (+0,+32,+64,+96 bytes), NO waitcnt.
#define POLL4(e0,e1,e2,e3,bp)                                              \
    asm volatile("global_load_dword %0, %4, off sc0 sc1\n\t"               \
                 "global_load_dword %1, %4, off offset:32 sc0 sc1\n\t"     \
                 "global_load_dword %2, %4, off offset:64 sc0 sc1\n\t"     \
                 "global_load_dword %3, %4, off offset:96 sc0 sc1"         \
                 : "=&v"(e0), "=&v"(e1), "=&v"(e2), "=&v"(e3)              \
                 : "v"(bp) : "memory")

__global__ void __launch_bounds__(NTHR) hmm_fwd(
    const int*   __restrict__ obs,
    const float* __restrict__ A,
    const float* __restrict__ B,
    const float* __restrict__ pi,
    float*       __restrict__ out,
    unsigned*    __restrict__ flag)
{
    __shared__ float4 s_wpart[16][8];    // 2 KB per-wave partials
    __shared__ int    s_nz[4];           // depth-4 parity "row nonzero"

    const int tx   = threadIdx.x;
    const int b    = blockIdx.x;
    const int lane = tx & 63;
    const int w    = tx >> 6;            // wave id 0..15
    const int jl4  = lane & 7;           // col float4 within block (0..7)
    const int r_l  = lane >> 3;          // row-within-group (0..7)
    const int col4 = b * 8 + jl4;
    const float4* A4 = (const float4*)A;

    // ---- step 0 FIRST: publish encoded alpha0 chunk = pi * B[:, obs[0]] ----
    // (before the A-hoist, so the cross-block chain starts ~4-5us earlier)
    if (tx < 8) {
        const int o0 = obs[0];
        const int j  = b * 32 + tx * 4;
        v4i e;
        e.x = __float_as_int(pi[j + 0] * B[(size_t)(j + 0) * NSYM + o0]) + READY;
        e.y = __float_as_int(pi[j + 1] * B[(size_t)(j + 1) * NSYM + o0]) + READY;
        e.z = __float_as_int(pi[j + 2] * B[(size_t)(j + 2) * NSYM + o0]) + READY;
        e.w = __float_as_int(pi[j + 3] * B[(size_t)(j + 3) * NSYM + o0]) + READY;
        store_coherent_i4((int*)out + j, e);
    }
    if (tx == 0) { s_nz[0] = 0; s_nz[1] = 0; s_nz[2] = 0; s_nz[3] = 0; }
    __syncthreads();

    // ---- hoist the block's A slice into registers: a[q][s] = A4[i][col4],
    //      i = (w+16q)*32 + s*8 + r_l  (step-invariant) ----
    float4 a_reg[4][4];
    #pragma unroll
    for (int q = 0; q < 4; ++q)
        #pragma unroll
        for (int s = 0; s < 4; ++s) {
            const int i = (w + 16 * q) * 32 + s * 8 + r_l;
            a_reg[q][s] = A4[(size_t)i * (S / 4) + col4];
        }

    int lastRow = T - 1;

    for (int t = 1; t < T; ++t) {
        // ---- emission prefetch (wave0 lanes; same lanes publish later) ----
        float em0 = 0.f, em1 = 0.f, em2 = 0.f, em3 = 0.f;
        if (tx < 8) {
            const int o = obs[t];
            const int j = b * 32 + tx * 4;
            em0 = B[(size_t)(j + 0) * NSYM + o];
            em1 = B[(size_t)(j + 1) * NSYM + o];
            em2 = B[(size_t)(j + 2) * NSYM + o];
            em3 = B[(size_t)(j + 3) * NSYM + o];
        }

        // ---- batch-poll this wave's 16 encoded alpha scalars of row t-1 ----
        const int* rb = (const int*)(out + (size_t)(t - 1) * S) + r_l;
        const int* b0 = rb + (w +  0) * 32;
        const int* b1 = rb + (w + 16) * 32;
        const int* b2 = rb + (w + 32) * 32;
        const int* b3 = rb + (w + 48) * 32;
        int e00, e01, e02, e03, e10, e11, e12, e13;
        int e20, e21, e22, e23, e30, e31, e32, e33;
        for (;;) {
            POLL4(e00, e01, e02, e03, b0);
            POLL4(e10, e11, e12, e13, b1);
            POLL4(e20, e21, e22, e23, b2);
            POLL4(e30, e31, e32, e33, b3);
            asm volatile("s_waitcnt vmcnt(0)" ::: "memory");
            const int m0 = (e00 < READY) | (e01 < READY) | (e02 < READY) | (e03 < READY);
            const int m1 = (e10 < READY) | (e11 < READY) | (e12 < READY) | (e13 < READY);
            const int m2 = (e20 < READY) | (e21 < READY) | (e22 < READY) | (e23 < READY);
            const int m3 = (e30 < READY) | (e31 < READY) | (e32 < READY) | (e33 < READY);
            if (!(m0 | m1 | m2 | m3)) break;
        }

        // ---- decode + FMA vs register-resident A ----
        float4 acc = make_float4(0.f, 0.f, 0.f, 0.f);
        int nzacc = 0;
        #define STEP1(E, Q, Ss)                                                \
            { const int d = (E) - READY; nzacc |= d;                           \
              const float af = __int_as_float(d);                              \
              acc.x = fmaf(af, a_reg[Q][Ss].x, acc.x);                         \
              acc.y = fmaf(af, a_reg[Q][Ss].y, acc.y);                         \
              acc.z = fmaf(af, a_reg[Q][Ss].z, acc.z);                         \
              acc.w = fmaf(af, a_reg[Q][Ss].w, acc.w); }
        STEP1(e00,0,0) STEP1(e01,0,1) STEP1(e02,0,2) STEP1(e03,0,3)
        STEP1(e10,1,0) STEP1(e11,1,1) STEP1(e12,1,2) STEP1(e13,1,3)
        STEP1(e20,2,0) STEP1(e21,2,1) STEP1(e22,2,2) STEP1(e23,2,3)
        STEP1(e30,3,0) STEP1(e31,3,1) STEP1(e32,3,2) STEP1(e33,3,3)
        #undef STEP1

        // in-wave reduce over lane bits 3,4,5 (the 8 r_l groups)
        #pragma unroll
        for (int m = 8; m <= 32; m <<= 1) {
            acc.x += __shfl_xor(acc.x, m);
            acc.y += __shfl_xor(acc.y, m);
            acc.z += __shfl_xor(acc.z, m);
            acc.w += __shfl_xor(acc.w, m);
        }
        if (lane < 8) s_wpart[w][lane] = acc;
        const unsigned long long nzm = __ballot(nzacc != 0);
        if (nzm != 0ull && lane == 0) s_nz[t & 3] = 1;   // benign same-value race
        if (tx == 0) s_nz[(t + 2) & 3] = 0;              // prep 2 steps ahead
        __syncthreads();                                 // the ONLY per-step barrier

        if (s_nz[t & 3] == 0) { lastRow = t - 1; break; }   // uniform everywhere

        // ---- wave0: combine 16 wave-partials, emission-multiply, publish ----
        if (tx < 64) {
            const int h = tx >> 3, c = tx & 7;
            float4 p = s_wpart[h][c];
            const float4 q4 = s_wpart[h + 8][c];
            p.x += q4.x; p.y += q4.y; p.z += q4.z; p.w += q4.w;
            #pragma unroll
            for (int m = 8; m <= 32; m <<= 1) {
                p.x += __shfl_xor(p.x, m);
                p.y += __shfl_xor(p.y, m);
                p.z += __shfl_xor(p.z, m);
                p.w += __shfl_xor(p.w, m);
            }
            if (tx < 8) {
                v4i e;
                e.x = __float_as_int(p.x * em0) + READY;
                e.y = __float_as_int(p.y * em1) + READY;
                e.z = __float_as_int(p.z * em2) + READY;
                e.w = __float_as_int(p.w * em3) + READY;
                store_coherent_i4((int*)(out + (size_t)t * S) + b * 32 + tx * 4, e);
            }
        }
        // no bottom barrier: next step's polls gate progress (R7/R8-proven).
    }

    // ---- publish zstart; kernel boundary handles all ordering/visibility ----
    if (tx == 0)
        __hip_atomic_store(&flag[0], (unsigned)(lastRow + 1), __ATOMIC_RELAXED,
                           __HIP_MEMORY_SCOPE_AGENT);
}

// k2: decode rows [0, zstart), zero rows [zstart, T). Stream-ordered after k1;
// the kernel boundary guarantees k1's device-scope stores are visible to
// plain loads here (L1s start invalidated, stores drained at kernel end).
__global__ void __launch_bounds__(NTHR) hmm_tail(
    float*          __restrict__ out,
    const unsigned* __restrict__ flag)
{
    const unsigned zstart = flag[0];                 // lastRow+1
    const size_t total4 = (size_t)T * (S / 4);       // float4 count
    v4i* o4 = (v4i*)out;
    const v4i zero = {0, 0, 0, 0};
    for (size_t i = (size_t)blockIdx.x * NTHR + threadIdx.x; i < total4;
         i += (size_t)FBLK * NTHR) {
        const unsigned r = (unsigned)(i >> 9);       // S/4 = 512 float4 per row
        if (r >= zstart) {
            o4[i] = zero;                            // plain coalesced store
        } else {
            v4i e = o4[i];                           // plain load (post-barrier)
            e.x -= READY; e.y -= READY; e.z -= READY; e.w -= READY;
            o4[i] = e;
        }
    }
}

extern "C" void kernel_launch(void* const* d_in, const int* in_sizes, int n_in,
                              void* d_out, int out_size, void* d_ws, size_t ws_size,
                              hipStream_t stream) {
    const int*   obs = (const int*)d_in[0];
    const float* A   = (const float*)d_in[1];
    const float* B   = (const float*)d_in[2];
    const float* pi  = (const float*)d_in[3];
    float* out = (float*)d_out;
    unsigned* flag = (unsigned*)d_ws;

    // d_ws is poisoned before every launch; zstart word must start defined.
    (void)hipMemsetAsync(d_ws, 0, 4 * sizeof(unsigned), stream);

    hmm_fwd<<<dim3(NCBLK), dim3(NTHR), 0, stream>>>(obs, A, B, pi, out, flag);
    hmm_tail<<<dim3(FBLK), dim3(NTHR), 0, stream>>>(out, flag);
}